// Round 7
// baseline (1704925.586 us; speedup 1.0000x reference)
//
#include <hip/hip_runtime.h>
#include <stdint.h>

typedef unsigned int u32;
typedef unsigned short u16;
typedef __attribute__((ext_vector_type(8))) __bf16 bf16x8;
typedef __attribute__((ext_vector_type(4))) float f32x4;
typedef __attribute__((ext_vector_type(4))) u32 u32x4;
typedef __attribute__((ext_vector_type(2))) u32 u32x2;

#define NSTEPS 256
// ---- workspace layout ----
#define XB_BYTES   67108864u              // x as bf16: 512*256*256*2
#define SL_OFF     XB_BYTES               // h slots: [slot][group][wgN][row][c16] bf16
#define GRP_BYTES   65536u                // 32 wgN * 2048B
#define SLOT_BYTES  524288u               // 8 groups
#define CNT_OFF    (SL_OFF + 2u * SLOT_BYTES)   // cnt[grp] @ +grp*128 (NEVER memset)
#define READY_OFF  (CNT_OFF + 2048u)            // launch barrier (memset each launch)
#define DISC_OFF   (CNT_OFF + 4096u)            // u32[256] raw XCC ids
// ---- LDS: fragment-linear weights ----
#define LDS_TOTAL 98304                   // 4*24*64*16

static __device__ __forceinline__ u16 f2bf(float f) {
  u32 u = __builtin_bit_cast(u32, f);
  return (u16)((u + 0x7fffu + ((u >> 16) & 1u)) >> 16);   // RNE
}
static __device__ __forceinline__ float bf2f(u16 h) {
  u32 u = ((u32)h) << 16;
  return __builtin_bit_cast(float, u);
}
static __device__ __forceinline__ float sigm(float x) {
  return __builtin_amdgcn_rcpf(1.f + __builtin_amdgcn_exp2f(-1.4426950408889634f * x));
}
static __device__ __forceinline__ float tanh_(float x) {
  return 1.f - 2.f * __builtin_amdgcn_rcpf(1.f + __builtin_amdgcn_exp2f(2.8853900817779268f * x));
}

// device-scope poll (always sc0 sc1)
static __device__ __forceinline__ u32 poll_dev(const u32* p) {
  u32 v;
  asm volatile("global_load_dword %0, %1, off sc0 sc1\n\ts_waitcnt vmcnt(0)"
               : "=v"(v) : "v"(p) : "memory");
  return v;
}
// scope-templated primitives: L2=true -> sc0 (XCD-local L2); false -> sc0 sc1 (device)
template<bool L2> static __device__ __forceinline__ u32 pollT(const u32* p) {
  u32 v;
  if constexpr (L2)
    asm volatile("global_load_dword %0, %1, off sc0\n\ts_waitcnt vmcnt(0)"
                 : "=v"(v) : "v"(p) : "memory");
  else
    asm volatile("global_load_dword %0, %1, off sc0 sc1\n\ts_waitcnt vmcnt(0)"
                 : "=v"(v) : "v"(p) : "memory");
  return v;
}
template<bool L2> static __device__ __forceinline__ void st8T(void* p, u32x2 v) {
  if constexpr (L2)
    asm volatile("global_store_dwordx2 %0, %1, off sc0" :: "v"(p), "v"(v) : "memory");
  else
    asm volatile("global_store_dwordx2 %0, %1, off sc0 sc1" :: "v"(p), "v"(v) : "memory");
}
template<bool L2> static __device__ __forceinline__ u32x4 ld16T(const void* p) {
  u32x4 v;
  if constexpr (L2)
    asm volatile("global_load_dwordx4 %0, %1, off sc0\n\ts_waitcnt vmcnt(0)"
                 : "=v"(v) : "v"(p) : "memory");
  else
    asm volatile("global_load_dwordx4 %0, %1, off sc0 sc1\n\ts_waitcnt vmcnt(0)"
                 : "=v"(v) : "v"(p) : "memory");
  return v;
}
#define AISSUE_BODY(SC) \
    "global_load_dwordx4 %0, %16, off " SC "\n\t"  "global_load_dwordx4 %1, %17, off " SC "\n\t" \
    "global_load_dwordx4 %2, %18, off " SC "\n\t"  "global_load_dwordx4 %3, %19, off " SC "\n\t" \
    "global_load_dwordx4 %4, %20, off " SC "\n\t"  "global_load_dwordx4 %5, %21, off " SC "\n\t" \
    "global_load_dwordx4 %6, %22, off " SC "\n\t"  "global_load_dwordx4 %7, %23, off " SC "\n\t" \
    "global_load_dwordx4 %8, %24, off " SC "\n\t"  "global_load_dwordx4 %9, %25, off " SC "\n\t" \
    "global_load_dwordx4 %10, %26, off " SC "\n\t" "global_load_dwordx4 %11, %27, off " SC "\n\t" \
    "global_load_dwordx4 %12, %28, off " SC "\n\t" "global_load_dwordx4 %13, %29, off " SC "\n\t" \
    "global_load_dwordx4 %14, %30, off " SC "\n\t" "global_load_dwordx4 %15, %31, off " SC
#define AISSUE_OPS(s, b) \
    : "=&v"(s[0]), "=&v"(s[1]), "=&v"(s[2]), "=&v"(s[3]), \
      "=&v"(s[4]), "=&v"(s[5]), "=&v"(s[6]), "=&v"(s[7]), \
      "=&v"(s[8]), "=&v"(s[9]), "=&v"(s[10]), "=&v"(s[11]), \
      "=&v"(s[12]), "=&v"(s[13]), "=&v"(s[14]), "=&v"(s[15]) \
    : "v"(b), "v"(b + 4096), "v"(b + 8192), "v"(b + 12288), \
      "v"(b + 16384), "v"(b + 20480), "v"(b + 24576), "v"(b + 28672), \
      "v"(b + 32768), "v"(b + 36864), "v"(b + 40960), "v"(b + 45056), \
      "v"(b + 49152), "v"(b + 53248), "v"(b + 57344), "v"(b + 61440) \
    : "memory"
template<bool L2> static __device__ __forceinline__ void aissueT(u32x4 s[16], const char* b) {
  if constexpr (L2) asm volatile(AISSUE_BODY("sc0")     AISSUE_OPS(s, b));
  else              asm volatile(AISSUE_BODY("sc0 sc1") AISSUE_OPS(s, b));
}
// issue 8 cached x loads (no wait)
static __device__ __forceinline__ void xissue(u32x4 x[8], const void* base) {
  asm volatile(
    "global_load_dwordx4 %0, %8, off offset:0\n\t"
    "global_load_dwordx4 %1, %8, off offset:64\n\t"
    "global_load_dwordx4 %2, %8, off offset:128\n\t"
    "global_load_dwordx4 %3, %8, off offset:192\n\t"
    "global_load_dwordx4 %4, %8, off offset:256\n\t"
    "global_load_dwordx4 %5, %8, off offset:320\n\t"
    "global_load_dwordx4 %6, %8, off offset:384\n\t"
    "global_load_dwordx4 %7, %8, off offset:448"
    : "=&v"(x[0]), "=&v"(x[1]), "=&v"(x[2]), "=&v"(x[3]),
      "=&v"(x[4]), "=&v"(x[5]), "=&v"(x[6]), "=&v"(x[7])
    : "v"(base) : "memory");
}
#define AWAIT(N) do { asm volatile("s_waitcnt vmcnt(" #N ")" ::: "memory"); \
                      __builtin_amdgcn_sched_barrier(0); } while (0)
// guarded poll: base-relative (stale/poison-proof), watchdog (deadlock -> fast-fail)
template<bool L2> static __device__ __forceinline__ void wait_ge(const u32* cnt, u32 base, u32 tgt) {
  int guard = 0;
  while ((u32)(pollT<L2>(cnt) - base) < tgt) {
    __builtin_amdgcn_s_sleep(1);
    if (++guard > (1 << 16)) break;
  }
}

__global__ void cvt_x(const float* __restrict__ x, u16* __restrict__ xb) {
  int i = blockIdx.x * 256 + threadIdx.x;
  float4 v = ((const float4*)x)[i];
  ushort4 o;
  o.x = f2bf(v.x); o.y = f2bf(v.y); o.z = f2bf(v.z); o.w = f2bf(v.w);
  ((ushort4*)xb)[i] = o;
}

template<bool L2>
static __device__ __forceinline__ void lstm_body(
    char* smem, const u16* __restrict__ xb,
    const float* __restrict__ W_ih, const float* __restrict__ W_hh,
    const float* __restrict__ b_ih, const float* __restrict__ b_hh,
    const float* __restrict__ W_out, const float* __restrict__ b_out,
    float* __restrict__ out, char* __restrict__ ws,
    int grp, int wgN, u32 base)
{
  const int tid = threadIdx.x;
  const int lane = tid & 63;
  const int wv   = tid >> 6;
  const int cc = lane & 15;
  const int hi = lane >> 4;

  // ---- one-time: weight slice -> LDS, fragment-linear (conflict-free) ----
  {
    const int lc = lane & 15, hh = lane >> 4;
    #pragma unroll
    for (int nt = 0; nt < 4; ++nt)
      #pragma unroll
      for (int it = 0; it < 6; ++it) {
        int kcc = wv + it * 4;                  // 0..23
        int n = nt * 512 + wgN * 16 + lc;
        int k = kcc * 32 + hh * 8;
        float4 v0, v1;
        if (kcc < 8) {
          v0 = *(const float4*)(W_ih + n * 256 + k);
          v1 = *(const float4*)(W_ih + n * 256 + k + 4);
        } else {
          int k2 = k - 256;
          v0 = *(const float4*)(W_hh + n * 512 + k2);
          v1 = *(const float4*)(W_hh + n * 512 + k2 + 4);
        }
        u32x4 g;
        g[0] = (u32)f2bf(v0.x) | ((u32)f2bf(v0.y) << 16);
        g[1] = (u32)f2bf(v0.z) | ((u32)f2bf(v0.w) << 16);
        g[2] = (u32)f2bf(v1.x) | ((u32)f2bf(v1.y) << 16);
        g[3] = (u32)f2bf(v1.z) | ((u32)f2bf(v1.w) << 16);
        *(u32x4*)(smem + ((nt * 24 + kcc) * 64 + lane) * 16) = g;
      }
  }

  float bvn[4][4];
  #pragma unroll
  for (int nt = 0; nt < 4; ++nt)
    #pragma unroll
    for (int r = 0; r < 4; ++r) {
      int n = nt * 512 + wgN * 16 + hi * 4 + r;
      bvn[nt][r] = b_ih[n] + b_hh[n];
    }

  u32* cnt = (u32*)(ws + CNT_OFF + grp * 128);
  char* slices = ws + SL_OFF;
  const char* grpsl = slices + (size_t)grp * GRP_BYTES;
  const u16* xrow = xb + (size_t)(grp * 64 + wv * 16 + cc) * 65536 + hi * 8;
  const int afrag = (hi >> 1) * 2048 + (wv * 16 + cc) * 32 + (hi & 1) * 16;

  __syncthreads();

  // ---- pin h-part weight fragments in 256 regs ----
  bf16x8 bh[16][4];
  #pragma unroll
  for (int kc = 0; kc < 16; ++kc)
    #pragma unroll
    for (int nt = 0; nt < 4; ++nt)
      bh[kc][nt] = *(const bf16x8*)(smem + ((nt * 24 + kc + 8) * 64 + lane) * 16);
  #pragma unroll
  for (int kc = 0; kc < 16; ++kc)
    #pragma unroll
    for (int nt = 0; nt < 4; ++nt)
      asm volatile("" : "+v"(bh[kc][nt]));

  float cst[4] = {0.f, 0.f, 0.f, 0.f};

  // ================= t = 0: x-part only (h_-1 = 0; no slot read) =================
  u32x4 xreg[8];
  xissue(xreg, xrow);
  AWAIT(0);
  {
    f32x4 acc[4] = {};
    #pragma unroll
    for (int kc = 0; kc < 8; ++kc) {
      bf16x8 b = __builtin_bit_cast(bf16x8, xreg[kc]);
      #pragma unroll
      for (int nt = 0; nt < 4; ++nt) {
        bf16x8 a = *(const bf16x8*)(smem + ((nt * 24 + kc) * 64 + lane) * 16);
        acc[nt] = __builtin_amdgcn_mfma_f32_16x16x32_bf16(a, b, acc[nt], 0, 0, 0);
      }
    }
    char* wdst = slices + grp * GRP_BYTES + wgN * 2048;      // slot 0
    u32 plo = 0, phi2 = 0;
    #pragma unroll
    for (int r = 0; r < 4; ++r) {
      float gi = acc[0][r] + bvn[0][r];
      float gf = acc[1][r] + bvn[1][r];
      float gg = acc[2][r] + bvn[2][r];
      float go = acc[3][r] + bvn[3][r];
      float ii = sigm(gi), ff = sigm(gf), g2 = tanh_(gg), oo = sigm(go);
      float cn = ff * cst[r] + ii * g2;
      cst[r] = cn;
      float hn = oo * tanh_(cn);
      u32 hb = (u32)f2bf(hn);
      if (r < 2) plo |= hb << (16 * r);
      else       phi2 |= hb << (16 * (r - 2));
    }
    u32x2 pk; pk[0] = plo; pk[1] = phi2;
    st8T<L2>(wdst + (wv * 16 + cc) * 32 + hi * 8, pk);
    AWAIT(0);
    __syncthreads();
    if (tid == 0) {
      if constexpr (L2)
        __hip_atomic_fetch_add(cnt, 1u, __ATOMIC_RELAXED, __HIP_MEMORY_SCOPE_WORKGROUP);
      else
        atomicAdd(cnt, 1u);
    }
    xissue(xreg, xrow + 256);                                // prefetch x_1
  }

  // ================= t = 1..255 =================
  #pragma unroll 1
  for (int t = 1; t < NSTEPS; ++t) {
    wait_ge<L2>(cnt, base, 32u * (u32)t);

    const char* rds = grpsl + (size_t)((t & 1) ^ 1) * SLOT_BYTES;
    u32x4 av[16];
    aissueT<L2>(av, rds + afrag);

    AWAIT(16);
    f32x4 acc[4] = {};
    #pragma unroll
    for (int kc = 0; kc < 8; ++kc) {
      bf16x8 b = __builtin_bit_cast(bf16x8, xreg[kc]);
      #pragma unroll
      for (int nt = 0; nt < 4; ++nt) {
        bf16x8 a = *(const bf16x8*)(smem + ((nt * 24 + kc) * 64 + lane) * 16);
        acc[nt] = __builtin_amdgcn_mfma_f32_16x16x32_bf16(a, b, acc[nt], 0, 0, 0);
      }
    }

    AWAIT(12);
    #pragma unroll
    for (int kc = 0; kc < 4; ++kc) {
      bf16x8 b = __builtin_bit_cast(bf16x8, av[kc]);
      #pragma unroll
      for (int nt = 0; nt < 4; ++nt)
        acc[nt] = __builtin_amdgcn_mfma_f32_16x16x32_bf16(bh[kc][nt], b, acc[nt], 0, 0, 0);
    }
    AWAIT(8);
    #pragma unroll
    for (int kc = 4; kc < 8; ++kc) {
      bf16x8 b = __builtin_bit_cast(bf16x8, av[kc]);
      #pragma unroll
      for (int nt = 0; nt < 4; ++nt)
        acc[nt] = __builtin_amdgcn_mfma_f32_16x16x32_bf16(bh[kc][nt], b, acc[nt], 0, 0, 0);
    }
    AWAIT(4);
    #pragma unroll
    for (int kc = 8; kc < 12; ++kc) {
      bf16x8 b = __builtin_bit_cast(bf16x8, av[kc]);
      #pragma unroll
      for (int nt = 0; nt < 4; ++nt)
        acc[nt] = __builtin_amdgcn_mfma_f32_16x16x32_bf16(bh[kc][nt], b, acc[nt], 0, 0, 0);
    }
    AWAIT(0);
    #pragma unroll
    for (int kc = 12; kc < 16; ++kc) {
      bf16x8 b = __builtin_bit_cast(bf16x8, av[kc]);
      #pragma unroll
      for (int nt = 0; nt < 4; ++nt)
        acc[nt] = __builtin_amdgcn_mfma_f32_16x16x32_bf16(bh[kc][nt], b, acc[nt], 0, 0, 0);
    }

    char* wdst = slices + (size_t)(t & 1) * SLOT_BYTES + grp * GRP_BYTES + wgN * 2048;
    u32 plo = 0, phi2 = 0;
    #pragma unroll
    for (int r = 0; r < 4; ++r) {
      float gi = acc[0][r] + bvn[0][r];
      float gf = acc[1][r] + bvn[1][r];
      float gg = acc[2][r] + bvn[2][r];
      float go = acc[3][r] + bvn[3][r];
      float ii = sigm(gi), ff = sigm(gf), g2 = tanh_(gg), oo = sigm(go);
      float cn = ff * cst[r] + ii * g2;
      cst[r] = cn;
      float hn = oo * tanh_(cn);
      u32 hb = (u32)f2bf(hn);
      if (r < 2) plo |= hb << (16 * r);
      else       phi2 |= hb << (16 * (r - 2));
    }
    u32x2 pk; pk[0] = plo; pk[1] = phi2;
    st8T<L2>(wdst + (wv * 16 + cc) * 32 + hi * 8, pk);

    AWAIT(0);
    __syncthreads();
    if (tid == 0) {
      if constexpr (L2)
        __hip_atomic_fetch_add(cnt, 1u, __ATOMIC_RELAXED, __HIP_MEMORY_SCOPE_WORKGROUP);
      else
        atomicAdd(cnt, 1u);
    }
    if (t + 1 < NSTEPS)
      xissue(xreg, xrow + (size_t)(t + 1) * 256);
  }

  // ---- head: wgN==0 of each group: out = h_T @ W_out^T + b_out ----
  if (wgN == 0) {
    wait_ge<L2>(cnt, base, 32u * NSTEPS);
    const char* src = grpsl + SLOT_BYTES;        // slot 1 = h_255
    int b = tid >> 2, q = tid & 3;
    float s = 0.f;
    #pragma unroll
    for (int j16 = 0; j16 < 8; ++j16) {
      int nblk = q * 8 + j16;
      const char* p = src + nblk * 2048 + b * 32;
      u32x4 w0 = ld16T<L2>(p);
      u32x4 w1 = ld16T<L2>(p + 16);
      #pragma unroll
      for (int d = 0; d < 4; ++d) {
        int jb = q * 128 + j16 * 16 + d * 2;
        s += bf2f((u16)(w0[d] & 0xffff)) * W_out[jb];
        s += bf2f((u16)(w0[d] >> 16))    * W_out[jb + 1];
        s += bf2f((u16)(w1[d] & 0xffff)) * W_out[jb + 8];
        s += bf2f((u16)(w1[d] >> 16))    * W_out[jb + 9];
      }
    }
    s += __shfl_xor(s, 1);
    s += __shfl_xor(s, 2);
    if (q == 0) out[grp * 64 + b] = s + b_out[0];
  }
}

__global__ void __launch_bounds__(256, 1) lstm_main(
    const u16* __restrict__ xb,
    const float* __restrict__ W_ih, const float* __restrict__ W_hh,
    const float* __restrict__ b_ih, const float* __restrict__ b_hh,
    const float* __restrict__ W_out, const float* __restrict__ b_out,
    float* __restrict__ out, char* __restrict__ ws)
{
  __shared__ char smem[LDS_TOTAL];
  __shared__ u32 badsum;
  const int tid = threadIdx.x;
  const int wg  = blockIdx.x;

  // ---- discovery: publish raw XCC id, read counter bases, grid barrier ----
  u32 raw;
  asm volatile("s_getreg_b32 %0, hwreg(HW_REG_XCC_ID)" : "=s"(raw));
  u32* ids     = (u32*)smem;           // [256]
  u32* basebuf = (u32*)(smem + 1024);  // [16]: sc0 bases, then sc0sc1 bases
  u32* disc  = (u32*)(ws + DISC_OFF);
  u32* ready = (u32*)(ws + READY_OFF);
  if (tid == 0) {
    #pragma unroll
    for (int g = 0; g < 8; ++g) {      // bases BEFORE ready-signal (pre-increment)
      u32 b0, b1;
      const u32* cp = (const u32*)(ws + CNT_OFF + g * 128);
      asm volatile("global_load_dword %0, %2, off sc0\n\t"
                   "global_load_dword %1, %2, off sc0 sc1\n\t"
                   "s_waitcnt vmcnt(0)"
                   : "=&v"(b0), "=&v"(b1) : "v"(cp) : "memory");
      basebuf[g] = b0; basebuf[8 + g] = b1;
    }
    asm volatile("global_store_dword %0, %1, off sc0 sc1\n\ts_waitcnt vmcnt(0)"
                 :: "v"(disc + wg), "v"(raw) : "memory");
    atomicAdd(ready, 1u);
    int guard = 0;
    while (poll_dev(ready) < 256u) {
      __builtin_amdgcn_s_sleep(8);
      if (++guard > (1 << 20)) break;
    }
    badsum = 0;
  }
  __syncthreads();
  {
    u32 v; const u32* p = disc + tid;
    asm volatile("global_load_dword %0, %1, off sc0 sc1\n\ts_waitcnt vmcnt(0)"
                 : "=v"(v) : "v"(p) : "memory");
    ids[tid] = v;
  }
  __syncthreads();
  u32 myid = ids[wg], tval = ids[tid];
  int cless = 0, cbefore = 0, occ = 0; u32 bad = 0;
  for (int j = 0; j < 256; ++j) {
    u32 v = ids[j];
    cless   += (v < myid) ? 1 : 0;
    cbefore += (v == myid && j < wg) ? 1 : 0;
    occ     += (v == tval) ? 1 : 0;
    bad     |= (v > 7u) ? 1u : 0u;
  }
  if (occ != 32 || bad) atomicOr(&badsum, 1u);
  __syncthreads();
  const bool l2mode = (badsum == 0);
  const int grpL = cless >> 5;
  const u32 baseL = basebuf[grpL & 7];
  const u32 baseF = basebuf[8 + (wg & 7)];
  const int wgNL = cbefore;
  __syncthreads();   // smem reused for weights inside body

  if (l2mode)
    lstm_body<true>(smem, xb, W_ih, W_hh, b_ih, b_hh, W_out, b_out, out, ws,
                    grpL, wgNL, baseL);
  else
    lstm_body<false>(smem, xb, W_ih, W_hh, b_ih, b_hh, W_out, b_out, out, ws,
                     wg & 7, wg >> 3, baseF);
}

extern "C" void kernel_launch(void* const* d_in, const int* in_sizes, int n_in,
                              void* d_out, int out_size, void* d_ws, size_t ws_size,
                              hipStream_t stream) {
  (void)in_sizes; (void)n_in; (void)out_size; (void)ws_size;
  const float* x     = (const float*)d_in[0];
  const float* W_ih  = (const float*)d_in[1];
  const float* W_hh  = (const float*)d_in[2];
  const float* b_ih  = (const float*)d_in[3];
  const float* b_hh  = (const float*)d_in[4];
  const float* W_out = (const float*)d_in[5];
  const float* b_out = (const float*)d_in[6];
  char* ws = (char*)d_ws;

  // only the launch barrier needs zeroing (cnt is base-relative; slots are
  // never read before being written this launch)
  hipMemsetAsync(ws + READY_OFF, 0, 256, stream);
  cvt_x<<<32768, 256, 0, stream>>>(x, (u16*)ws);
  lstm_main<<<256, 256, 0, stream>>>((const u16*)ws, W_ih, W_hh, b_ih, b_hh,
                                     W_out, b_out, (float*)d_out, ws);
}

// Round 11
// 2323.634 us; speedup vs baseline: 733.7323x; 733.7323x over previous
//
#include <hip/hip_runtime.h>
#include <stdint.h>

typedef unsigned int u32;
typedef unsigned short u16;
typedef __attribute__((ext_vector_type(8))) __bf16 bf16x8;
typedef __attribute__((ext_vector_type(4))) float f32x4;
typedef __attribute__((ext_vector_type(4))) u32 u32x4;
typedef __attribute__((ext_vector_type(2))) u32 u32x2;

#define NSTEPS 256
// ---- workspace layout ----
#define XB_BYTES   67108864u              // x as bf16: 512*256*256*2
#define SL_OFF     XB_BYTES               // h slots: 2 x [group][wgN][row][c16] bf16
#define GRP_BYTES   65536u                // 32 wgN * 2048B
#define SLOT_BYTES  524288u               // 8 groups
#define TAG_OFF    (SL_OFF + 2u * SLOT_BYTES)   // tag[grp][wv][wgN]: grp*512+wv*128+wgN*4
// ---- LDS: fragment-linear weights ----
#define LDS_TOTAL 98304                   // 4*24*64*16

static __device__ __forceinline__ u16 f2bf(float f) {
  u32 u = __builtin_bit_cast(u32, f);
  return (u16)((u + 0x7fffu + ((u >> 16) & 1u)) >> 16);   // RNE
}
static __device__ __forceinline__ float bf2f(u16 h) {
  u32 u = ((u32)h) << 16;
  return __builtin_bit_cast(float, u);
}
static __device__ __forceinline__ float sigm(float x) {
  return __builtin_amdgcn_rcpf(1.f + __builtin_amdgcn_exp2f(-1.4426950408889634f * x));
}
static __device__ __forceinline__ float tanh_(float x) {
  return 1.f - 2.f * __builtin_amdgcn_rcpf(1.f + __builtin_amdgcn_exp2f(2.8853900817779268f * x));
}

// device-coherent primitives (proven transport, R2-R5)
static __device__ __forceinline__ u32 poll_sc(const u32* p) {
  u32 v;
  asm volatile("global_load_dword %0, %1, off sc0 sc1\n\ts_waitcnt vmcnt(0)"
               : "=v"(v) : "v"(p) : "memory");
  return v;
}
static __device__ __forceinline__ void st8_sc(void* p, u32x2 v) {
  asm volatile("global_store_dwordx2 %0, %1, off sc0 sc1" :: "v"(p), "v"(v) : "memory");
}
static __device__ __forceinline__ u32x4 ld16_sc_wait(const void* p) {
  u32x4 v;
  asm volatile("global_load_dwordx4 %0, %1, off sc0 sc1\n\ts_waitcnt vmcnt(0)"
               : "=v"(v) : "v"(p) : "memory");
  return v;
}
// issue 8 cached x loads (no wait)
static __device__ __forceinline__ void xissue(u32x4 x[8], const void* base) {
  asm volatile(
    "global_load_dwordx4 %0, %8, off offset:0\n\t"
    "global_load_dwordx4 %1, %8, off offset:64\n\t"
    "global_load_dwordx4 %2, %8, off offset:128\n\t"
    "global_load_dwordx4 %3, %8, off offset:192\n\t"
    "global_load_dwordx4 %4, %8, off offset:256\n\t"
    "global_load_dwordx4 %5, %8, off offset:320\n\t"
    "global_load_dwordx4 %6, %8, off offset:384\n\t"
    "global_load_dwordx4 %7, %8, off offset:448"
    : "=&v"(x[0]), "=&v"(x[1]), "=&v"(x[2]), "=&v"(x[3]),
      "=&v"(x[4]), "=&v"(x[5]), "=&v"(x[6]), "=&v"(x[7])
    : "v"(base) : "memory");
}
// issue 16 device-coherent h-fragment loads (no wait); stride 4096 B (kc)
static __device__ __forceinline__ void aissue(u32x4 s[16], const char* b) {
  asm volatile(
    "global_load_dwordx4 %0, %16, off sc0 sc1\n\t"
    "global_load_dwordx4 %1, %17, off sc0 sc1\n\t"
    "global_load_dwordx4 %2, %18, off sc0 sc1\n\t"
    "global_load_dwordx4 %3, %19, off sc0 sc1\n\t"
    "global_load_dwordx4 %4, %20, off sc0 sc1\n\t"
    "global_load_dwordx4 %5, %21, off sc0 sc1\n\t"
    "global_load_dwordx4 %6, %22, off sc0 sc1\n\t"
    "global_load_dwordx4 %7, %23, off sc0 sc1\n\t"
    "global_load_dwordx4 %8, %24, off sc0 sc1\n\t"
    "global_load_dwordx4 %9, %25, off sc0 sc1\n\t"
    "global_load_dwordx4 %10, %26, off sc0 sc1\n\t"
    "global_load_dwordx4 %11, %27, off sc0 sc1\n\t"
    "global_load_dwordx4 %12, %28, off sc0 sc1\n\t"
    "global_load_dwordx4 %13, %29, off sc0 sc1\n\t"
    "global_load_dwordx4 %14, %30, off sc0 sc1\n\t"
    "global_load_dwordx4 %15, %31, off sc0 sc1"
    : "=&v"(s[0]), "=&v"(s[1]), "=&v"(s[2]), "=&v"(s[3]),
      "=&v"(s[4]), "=&v"(s[5]), "=&v"(s[6]), "=&v"(s[7]),
      "=&v"(s[8]), "=&v"(s[9]), "=&v"(s[10]), "=&v"(s[11]),
      "=&v"(s[12]), "=&v"(s[13]), "=&v"(s[14]), "=&v"(s[15])
    : "v"(b), "v"(b + 4096), "v"(b + 8192), "v"(b + 12288),
      "v"(b + 16384), "v"(b + 20480), "v"(b + 24576), "v"(b + 28672),
      "v"(b + 32768), "v"(b + 36864), "v"(b + 40960), "v"(b + 45056),
      "v"(b + 49152), "v"(b + 53248), "v"(b + 57344), "v"(b + 61440)
    : "memory");
}
#define AWAIT(N) do { asm volatile("s_waitcnt vmcnt(" #N ")" ::: "memory"); \
                      __builtin_amdgcn_sched_barrier(0); } while (0)

// poll the 32 tags of this wave's plane (lane&31 -> tag[wgN']) until all >= want
static __device__ __forceinline__ void wait_tags(const u32* p, u32 want) {
  int guard = 0;
  u32 v = poll_sc(p);
  while (!__all((int)(v >= want))) {
    if (++guard > (1 << 16)) break;       // watchdog: fail fast, never hang
    v = poll_sc(p);
  }
}

__global__ void cvt_x(const float* __restrict__ x, u16* __restrict__ xb) {
  int i = blockIdx.x * 256 + threadIdx.x;
  float4 v = ((const float4*)x)[i];
  ushort4 o;
  o.x = f2bf(v.x); o.y = f2bf(v.y); o.z = f2bf(v.z); o.w = f2bf(v.w);
  ((ushort4*)xb)[i] = o;
}

// 256 WGs: group = wg&7 (batch rows [grp*64,+64)), wgN = wg>>3 (hidden cols
// [wgN*16,+16) of all 4 gates). Swapped MFMA (D = W·X^T). Per-(grp,wv,wgN)
// tag words, signaled via ATOMIC add (the empirically-reliable ordered path:
// R2/R4/R5 passed with store->drain->atomic; plain-store signal NaN'd 3x).
// Wave-autonomous planes: no shared counter, no __syncthreads in t-loop.
__global__ void __launch_bounds__(256, 1) lstm_main(
    const u16* __restrict__ xb,
    const float* __restrict__ W_ih, const float* __restrict__ W_hh,
    const float* __restrict__ b_ih, const float* __restrict__ b_hh,
    const float* __restrict__ W_out, const float* __restrict__ b_out,
    float* __restrict__ out, char* __restrict__ ws)
{
  __shared__ char smem[LDS_TOTAL];
  const int tid = threadIdx.x;
  const int wg  = blockIdx.x;
  const int grp = wg & 7;
  const int wgN = wg >> 3;
  const int lane = tid & 63;
  const int wv   = tid >> 6;
  const int cc = lane & 15;
  const int hi = lane >> 4;

  // ---- one-time: weight slice -> LDS, fragment-linear (conflict-free) ----
  {
    const int lc = lane & 15, hh = lane >> 4;
    #pragma unroll
    for (int nt = 0; nt < 4; ++nt)
      #pragma unroll
      for (int it = 0; it < 6; ++it) {
        int kcc = wv + it * 4;                  // 0..23
        int n = nt * 512 + wgN * 16 + lc;
        int k = kcc * 32 + hh * 8;
        float4 v0, v1;
        if (kcc < 8) {
          v0 = *(const float4*)(W_ih + n * 256 + k);
          v1 = *(const float4*)(W_ih + n * 256 + k + 4);
        } else {
          int k2 = k - 256;
          v0 = *(const float4*)(W_hh + n * 512 + k2);
          v1 = *(const float4*)(W_hh + n * 512 + k2 + 4);
        }
        u32x4 g;
        g[0] = (u32)f2bf(v0.x) | ((u32)f2bf(v0.y) << 16);
        g[1] = (u32)f2bf(v0.z) | ((u32)f2bf(v0.w) << 16);
        g[2] = (u32)f2bf(v1.x) | ((u32)f2bf(v1.y) << 16);
        g[3] = (u32)f2bf(v1.z) | ((u32)f2bf(v1.w) << 16);
        *(u32x4*)(smem + ((nt * 24 + kcc) * 64 + lane) * 16) = g;
      }
  }

  float bvn[4][4];
  #pragma unroll
  for (int nt = 0; nt < 4; ++nt)
    #pragma unroll
    for (int r = 0; r < 4; ++r) {
      int n = nt * 512 + wgN * 16 + hi * 4 + r;
      bvn[nt][r] = b_ih[n] + b_hh[n];
    }

  char* slices = ws + SL_OFF;
  const char* grpsl = slices + (size_t)grp * GRP_BYTES;
  // own 8B data cell within a slot
  const size_t myoff = (size_t)grp * GRP_BYTES + wgN * 2048 + (wv * 16 + cc) * 32 + hi * 8;
  // per-lane read base inside a slot (stride 4096 per kc); plane-consistent:
  // rows (wv*16+cc) are written by producer wave wv of every WG
  const size_t rdoff = (size_t)grp * GRP_BYTES
                     + (hi >> 1) * 2048 + (wv * 16 + cc) * 32 + (hi & 1) * 16;
  const u16* xrow = xb + (size_t)(grp * 64 + wv * 16 + cc) * 65536 + hi * 8;

  // tag plane for this (grp, wv): 32 dwords, one per producer WG
  u32* tagplane = (u32*)(ws + TAG_OFF + grp * 512 + wv * 128);
  const u32* mypoll = tagplane + (lane & 31);
  u32* mytag = tagplane + wgN;

  __syncthreads();

  // ---- pin h-part weight fragments in 256 regs ----
  bf16x8 bh[16][4];
  #pragma unroll
  for (int kc = 0; kc < 16; ++kc)
    #pragma unroll
    for (int nt = 0; nt < 4; ++nt)
      bh[kc][nt] = *(const bf16x8*)(smem + ((nt * 24 + kc + 8) * 64 + lane) * 16);
  #pragma unroll
  for (int kc = 0; kc < 16; ++kc)
    #pragma unroll
    for (int nt = 0; nt < 4; ++nt)
      asm volatile("" : "+v"(bh[kc][nt]));      // opaque: forbid remat, force regs

  float cst[4] = {0.f, 0.f, 0.f, 0.f};

  // ============ t = 0: x-part only (h_-1 = 0); store h_0 -> slot 0; tag++ ====
  u32x4 xreg[8];
  xissue(xreg, xrow);
  AWAIT(0);
  {
    f32x4 acc[4] = {};
    #pragma unroll
    for (int kc = 0; kc < 8; ++kc) {
      bf16x8 b = __builtin_bit_cast(bf16x8, xreg[kc]);
      #pragma unroll
      for (int nt = 0; nt < 4; ++nt) {
        bf16x8 a = *(const bf16x8*)(smem + ((nt * 24 + kc) * 64 + lane) * 16);
        acc[nt] = __builtin_amdgcn_mfma_f32_16x16x32_bf16(a, b, acc[nt], 0, 0, 0);
      }
    }
    u32 plo = 0, phi2 = 0;
    #pragma unroll
    for (int r = 0; r < 4; ++r) {
      float gi = acc[0][r] + bvn[0][r];
      float gf = acc[1][r] + bvn[1][r];
      float gg = acc[2][r] + bvn[2][r];
      float go = acc[3][r] + bvn[3][r];
      float ii = sigm(gi), ff = sigm(gf), g2 = tanh_(gg), oo = sigm(go);
      float cn = ff * cst[r] + ii * g2;
      cst[r] = cn;
      float hn = oo * tanh_(cn);
      u32 hb = (u32)f2bf(hn);
      if (r < 2) plo |= hb << (16 * r);
      else       phi2 |= hb << (16 * (r - 2));
    }
    u32x2 pk; pk[0] = plo; pk[1] = phi2;
    st8_sc(slices + myoff, pk);                 // h_0 -> slot 0
    AWAIT(0);                                   // data store at coherence point
    if (lane == 0) atomicAdd(mytag, 1u);        // ATOMIC signal (ordered path)
    xissue(xreg, xrow + 256);                   // prefetch x_1 (overlaps next poll)
  }

  // ============ t = 1..255 ============
  #pragma unroll 1
  for (int t = 1; t < NSTEPS; ++t) {
    wait_tags(mypoll, (u32)t);                  // plane producers stored h_{t-1}
    // (poll's vmcnt(0) also drained the x_t prefetch)

    const char* rds = slices + (size_t)((t - 1) & 1) * SLOT_BYTES + rdoff;
    u32x4 av[16];
    aissue(av, rds);

    // x-part overlaps the h-load RTT
    f32x4 acc[4] = {};
    #pragma unroll
    for (int kc = 0; kc < 8; ++kc) {
      bf16x8 b = __builtin_bit_cast(bf16x8, xreg[kc]);
      #pragma unroll
      for (int nt = 0; nt < 4; ++nt) {
        bf16x8 a = *(const bf16x8*)(smem + ((nt * 24 + kc) * 64 + lane) * 16);
        acc[nt] = __builtin_amdgcn_mfma_f32_16x16x32_bf16(a, b, acc[nt], 0, 0, 0);
      }
    }

    // h-part from pinned weights, counted-vmcnt chunks
    AWAIT(12);
    #pragma unroll
    for (int kc = 0; kc < 4; ++kc) {
      bf16x8 b = __builtin_bit_cast(bf16x8, av[kc]);
      #pragma unroll
      for (int nt = 0; nt < 4; ++nt)
        acc[nt] = __builtin_amdgcn_mfma_f32_16x16x32_bf16(bh[kc][nt], b, acc[nt], 0, 0, 0);
    }
    AWAIT(8);
    #pragma unroll
    for (int kc = 4; kc < 8; ++kc) {
      bf16x8 b = __builtin_bit_cast(bf16x8, av[kc]);
      #pragma unroll
      for (int nt = 0; nt < 4; ++nt)
        acc[nt] = __builtin_amdgcn_mfma_f32_16x16x32_bf16(bh[kc][nt], b, acc[nt], 0, 0, 0);
    }
    AWAIT(4);
    #pragma unroll
    for (int kc = 8; kc < 12; ++kc) {
      bf16x8 b = __builtin_bit_cast(bf16x8, av[kc]);
      #pragma unroll
      for (int nt = 0; nt < 4; ++nt)
        acc[nt] = __builtin_amdgcn_mfma_f32_16x16x32_bf16(bh[kc][nt], b, acc[nt], 0, 0, 0);
    }
    AWAIT(0);
    #pragma unroll
    for (int kc = 12; kc < 16; ++kc) {
      bf16x8 b = __builtin_bit_cast(bf16x8, av[kc]);
      #pragma unroll
      for (int nt = 0; nt < 4; ++nt)
        acc[nt] = __builtin_amdgcn_mfma_f32_16x16x32_bf16(bh[kc][nt], b, acc[nt], 0, 0, 0);
    }

    // gates, pack, one 8B data store; FULL drain; atomic tag; then x prefetch
    u32 plo = 0, phi2 = 0;
    #pragma unroll
    for (int r = 0; r < 4; ++r) {
      float gi = acc[0][r] + bvn[0][r];
      float gf = acc[1][r] + bvn[1][r];
      float gg = acc[2][r] + bvn[2][r];
      float go = acc[3][r] + bvn[3][r];
      float ii = sigm(gi), ff = sigm(gf), g2 = tanh_(gg), oo = sigm(go);
      float cn = ff * cst[r] + ii * g2;
      cst[r] = cn;
      float hn = oo * tanh_(cn);
      u32 hb = (u32)f2bf(hn);
      if (r < 2) plo |= hb << (16 * r);
      else       phi2 |= hb << (16 * (r - 2));
    }
    u32x2 pk; pk[0] = plo; pk[1] = phi2;
    st8_sc(slices + (size_t)(t & 1) * SLOT_BYTES + myoff, pk);
    AWAIT(0);                                   // data store at coherence point
    if (lane == 0) atomicAdd(mytag, 1u);        // ATOMIC signal
    if (t + 1 < NSTEPS)
      xissue(xreg, xrow + (size_t)(t + 1) * 256);
  }

  // ---- head: wgN==0 of each group: out = h_255 @ W_out^T + b_out ----
  if (wgN == 0) {
    // wait for ALL planes (128 tags) to reach 256
    {
      const u32* tp = (const u32*)(ws + TAG_OFF + grp * 512) + (lane * 2);
      int guard = 0;
      for (;;) {
        u32 v0 = poll_sc(tp);
        u32 v1 = poll_sc(tp + 1);
        if (__all((int)((v0 >= NSTEPS) & (v1 >= NSTEPS)))) break;
        if (++guard > (1 << 16)) break;
      }
    }
    const char* src = grpsl + SLOT_BYTES;       // slot 255&1 = 1
    int b = tid >> 2, q = tid & 3;
    float s = 0.f;
    #pragma unroll 1
    for (int j16 = 0; j16 < 8; ++j16) {
      int nblk = q * 8 + j16;
      const char* p = src + nblk * 2048 + b * 32;
      u32x4 w0 = ld16_sc_wait(p);
      u32x4 w1 = ld16_sc_wait(p + 16);
      #pragma unroll
      for (int d = 0; d < 4; ++d) {
        int jb = q * 128 + j16 * 16 + d * 2;
        s += bf2f((u16)(w0[d] & 0xffff)) * W_out[jb];
        s += bf2f((u16)(w0[d] >> 16))    * W_out[jb + 1];
        s += bf2f((u16)(w1[d] & 0xffff)) * W_out[jb + 8];
        s += bf2f((u16)(w1[d] >> 16))    * W_out[jb + 9];
      }
    }
    s += __shfl_xor(s, 1);
    s += __shfl_xor(s, 2);
    if (q == 0) out[grp * 64 + b] = s + b_out[0];
  }
}

extern "C" void kernel_launch(void* const* d_in, const int* in_sizes, int n_in,
                              void* d_out, int out_size, void* d_ws, size_t ws_size,
                              hipStream_t stream) {
  (void)in_sizes; (void)n_in; (void)out_size; (void)ws_size;
  const float* x     = (const float*)d_in[0];
  const float* W_ih  = (const float*)d_in[1];
  const float* W_hh  = (const float*)d_in[2];
  const float* b_ih  = (const float*)d_in[3];
  const float* b_hh  = (const float*)d_in[4];
  const float* W_out = (const float*)d_in[5];
  const float* b_out = (const float*)d_in[6];
  char* ws = (char*)d_ws;

  // zero the tag planes each launch (atomic increments are launch-relative)
  hipMemsetAsync(ws + TAG_OFF, 0, 4096, stream);
  cvt_x<<<32768, 256, 0, stream>>>(x, (u16*)ws);
  lstm_main<<<256, 256, 0, stream>>>((const u16*)ws, W_ih, W_hh, b_ih, b_hh,
                                     W_out, b_out, (float*)d_out, ws);
}

// Round 13
// 1106.304 us; speedup vs baseline: 1541.1008x; 2.1004x over previous
//
#include <hip/hip_runtime.h>
#include <stdint.h>

typedef unsigned int u32;
typedef unsigned short u16;
typedef __attribute__((ext_vector_type(8))) __bf16 bf16x8;
typedef __attribute__((ext_vector_type(4))) float f32x4;
typedef __attribute__((ext_vector_type(4))) u32 u32x4;
typedef __attribute__((ext_vector_type(2))) u32 u32x2;

#define NSTEPS 256
// ---- workspace layout ----
#define XB_BYTES   67108864u              // x as bf16: 512*256*256*2
#define SL_OFF     XB_BYTES               // h slots: 2 x [group][wgN][row][c16] bf16
#define GRP_BYTES   65536u                // 32 wgN * 2048B
#define SLOT_BYTES  524288u               // 8 groups
#define CNT_OFF    (SL_OFF + 2u * SLOT_BYTES)
// ---- LDS: fragment-linear weights ----
#define LDS_TOTAL 98304                   // 4*24*64*16

static __device__ __forceinline__ u16 f2bf(float f) {
  u32 u = __builtin_bit_cast(u32, f);
  return (u16)((u + 0x7fffu + ((u >> 16) & 1u)) >> 16);   // RNE
}
static __device__ __forceinline__ float bf2f(u16 h) {
  u32 u = ((u32)h) << 16;
  return __builtin_bit_cast(float, u);
}
static __device__ __forceinline__ float sigm(float x) {
  return __builtin_amdgcn_rcpf(1.f + __builtin_amdgcn_exp2f(-1.4426950408889634f * x));
}
static __device__ __forceinline__ float tanh_(float x) {
  return 1.f - 2.f * __builtin_amdgcn_rcpf(1.f + __builtin_amdgcn_exp2f(2.8853900817779268f * x));
}

// device-coherent primitives (proven transport: observed-atomic-then-load)
static __device__ __forceinline__ u32 poll_sc(const u32* p) {
  u32 v;
  asm volatile("global_load_dword %0, %1, off sc0 sc1\n\ts_waitcnt vmcnt(0)"
               : "=v"(v) : "v"(p) : "memory");
  return v;
}
static __device__ __forceinline__ void st8_sc(void* p, u32x2 v) {
  asm volatile("global_store_dwordx2 %0, %1, off sc0 sc1" :: "v"(p), "v"(v) : "memory");
}
static __device__ __forceinline__ u32x4 ld16_sc_wait(const void* p) {
  u32x4 v;
  asm volatile("global_load_dwordx4 %0, %1, off sc0 sc1\n\ts_waitcnt vmcnt(0)"
               : "=v"(v) : "v"(p) : "memory");
  return v;
}
// issue 8 cached x loads (no wait)
static __device__ __forceinline__ void xissue(u32x4 x[8], const void* base) {
  asm volatile(
    "global_load_dwordx4 %0, %8, off offset:0\n\t"
    "global_load_dwordx4 %1, %8, off offset:64\n\t"
    "global_load_dwordx4 %2, %8, off offset:128\n\t"
    "global_load_dwordx4 %3, %8, off offset:192\n\t"
    "global_load_dwordx4 %4, %8, off offset:256\n\t"
    "global_load_dwordx4 %5, %8, off offset:320\n\t"
    "global_load_dwordx4 %6, %8, off offset:384\n\t"
    "global_load_dwordx4 %7, %8, off offset:448"
    : "=&v"(x[0]), "=&v"(x[1]), "=&v"(x[2]), "=&v"(x[3]),
      "=&v"(x[4]), "=&v"(x[5]), "=&v"(x[6]), "=&v"(x[7])
    : "v"(base) : "memory");
}
// issue 16 device-coherent h-fragment loads (no wait); stride 4096 B (kc)
static __device__ __forceinline__ void aissue(u32x4 s[16], const char* b) {
  asm volatile(
    "global_load_dwordx4 %0, %16, off sc0 sc1\n\t"
    "global_load_dwordx4 %1, %17, off sc0 sc1\n\t"
    "global_load_dwordx4 %2, %18, off sc0 sc1\n\t"
    "global_load_dwordx4 %3, %19, off sc0 sc1\n\t"
    "global_load_dwordx4 %4, %20, off sc0 sc1\n\t"
    "global_load_dwordx4 %5, %21, off sc0 sc1\n\t"
    "global_load_dwordx4 %6, %22, off sc0 sc1\n\t"
    "global_load_dwordx4 %7, %23, off sc0 sc1\n\t"
    "global_load_dwordx4 %8, %24, off sc0 sc1\n\t"
    "global_load_dwordx4 %9, %25, off sc0 sc1\n\t"
    "global_load_dwordx4 %10, %26, off sc0 sc1\n\t"
    "global_load_dwordx4 %11, %27, off sc0 sc1\n\t"
    "global_load_dwordx4 %12, %28, off sc0 sc1\n\t"
    "global_load_dwordx4 %13, %29, off sc0 sc1\n\t"
    "global_load_dwordx4 %14, %30, off sc0 sc1\n\t"
    "global_load_dwordx4 %15, %31, off sc0 sc1"
    : "=&v"(s[0]), "=&v"(s[1]), "=&v"(s[2]), "=&v"(s[3]),
      "=&v"(s[4]), "=&v"(s[5]), "=&v"(s[6]), "=&v"(s[7]),
      "=&v"(s[8]), "=&v"(s[9]), "=&v"(s[10]), "=&v"(s[11]),
      "=&v"(s[12]), "=&v"(s[13]), "=&v"(s[14]), "=&v"(s[15])
    : "v"(b), "v"(b + 4096), "v"(b + 8192), "v"(b + 12288),
      "v"(b + 16384), "v"(b + 20480), "v"(b + 24576), "v"(b + 28672),
      "v"(b + 32768), "v"(b + 36864), "v"(b + 40960), "v"(b + 45056),
      "v"(b + 49152), "v"(b + 53248), "v"(b + 57344), "v"(b + 61440)
    : "memory");
}
#define AWAIT(N) do { asm volatile("s_waitcnt vmcnt(" #N ")" ::: "memory"); \
                      __builtin_amdgcn_sched_barrier(0); } while (0)

__global__ void cvt_x(const float* __restrict__ x, u16* __restrict__ xb) {
  int i = blockIdx.x * 256 + threadIdx.x;          // one float4 per thread
  float4 v = ((const float4*)x)[i];
  ushort4 o;
  o.x = f2bf(v.x); o.y = f2bf(v.y); o.z = f2bf(v.z); o.w = f2bf(v.w);
  ((ushort4*)xb)[i] = o;
}

// 256 WGs: group = wg&7 (batch rows [grp*64,+64)), wgN = wg>>3 (hidden cols
// [wgN*16,+16) of all 4 gates). Swapped MFMA (D = W·X^T): lane holds
// batch=lane&15, hidden cols hi*4+r. h-part weights pinned in 256 regs;
// h fragments loaded directly from the global slot after observing the
// group counter (proven R5 protocol). R13 delta: only WAVE 0 polls the
// fabric counter; waves 1-3 spin on an LDS flag (4x less poll flood).
__global__ void __launch_bounds__(256, 1) lstm_main(
    const u16* __restrict__ xb,
    const float* __restrict__ W_ih, const float* __restrict__ W_hh,
    const float* __restrict__ b_ih, const float* __restrict__ b_hh,
    const float* __restrict__ W_out, const float* __restrict__ b_out,
    float* __restrict__ out, char* __restrict__ ws)
{
  __shared__ char smem[LDS_TOTAL];
  __shared__ u32 step_flag;
  const int tid = threadIdx.x;
  const int wg  = blockIdx.x;
  const int grp = wg & 7;
  const int wgN = wg >> 3;
  const int lane = tid & 63;
  const int wv   = tid >> 6;
  const int cc = lane & 15;
  const int hi = lane >> 4;

  if (tid == 0) step_flag = 0;

  // ---- one-time: weight slice -> LDS, fragment-linear (conflict-free) ----
  {
    const int lc = lane & 15, hh = lane >> 4;
    #pragma unroll
    for (int nt = 0; nt < 4; ++nt)
      #pragma unroll
      for (int it = 0; it < 6; ++it) {
        int kcc = wv + it * 4;                  // 0..23
        int n = nt * 512 + wgN * 16 + lc;
        int k = kcc * 32 + hh * 8;
        float4 v0, v1;
        if (kcc < 8) {
          v0 = *(const float4*)(W_ih + n * 256 + k);
          v1 = *(const float4*)(W_ih + n * 256 + k + 4);
        } else {
          int k2 = k - 256;
          v0 = *(const float4*)(W_hh + n * 512 + k2);
          v1 = *(const float4*)(W_hh + n * 512 + k2 + 4);
        }
        u32x4 g;
        g[0] = (u32)f2bf(v0.x) | ((u32)f2bf(v0.y) << 16);
        g[1] = (u32)f2bf(v0.z) | ((u32)f2bf(v0.w) << 16);
        g[2] = (u32)f2bf(v1.x) | ((u32)f2bf(v1.y) << 16);
        g[3] = (u32)f2bf(v1.z) | ((u32)f2bf(v1.w) << 16);
        *(u32x4*)(smem + ((nt * 24 + kcc) * 64 + lane) * 16) = g;
      }
  }

  float bvn[4][4];
  #pragma unroll
  for (int nt = 0; nt < 4; ++nt)
    #pragma unroll
    for (int r = 0; r < 4; ++r) {
      int n = nt * 512 + wgN * 16 + hi * 4 + r;
      bvn[nt][r] = b_ih[n] + b_hh[n];
    }

  u32* cnt = (u32*)(ws + CNT_OFF + grp * 128);
  char* slices = ws + SL_OFF;
  const char* grpsl = slices + (size_t)grp * GRP_BYTES;

  const u16* xrow = xb + (size_t)(grp * 64 + wv * 16 + cc) * 65536 + hi * 8;
  // A-fragment per-lane base inside slot (stride 4096 per kc)
  const int afrag = (hi >> 1) * 2048 + (wv * 16 + cc) * 32 + (hi & 1) * 16;

  __syncthreads();

  // ---- pin h-part weight fragments in 256 regs (kc 8..23 of full row) ----
  bf16x8 bh[16][4];
  #pragma unroll
  for (int kc = 0; kc < 16; ++kc)
    #pragma unroll
    for (int nt = 0; nt < 4; ++nt)
      bh[kc][nt] = *(const bf16x8*)(smem + ((nt * 24 + kc + 8) * 64 + lane) * 16);
  #pragma unroll
  for (int kc = 0; kc < 16; ++kc)
    #pragma unroll
    for (int nt = 0; nt < 4; ++nt)
      asm volatile("" : "+v"(bh[kc][nt]));      // opaque: forbid remat, force regs

  float cst[4] = {0.f, 0.f, 0.f, 0.f};          // fp32 cell state

  u32x4 xreg[8];
  xissue(xreg, xrow);                            // prefetch x_0

  #pragma unroll 1
  for (int t = 0; t < NSTEPS; ++t) {
    if (t > 0) {
      u32 tgt = 32u * (u32)t;
      if (wv == 0) {
        int guard = 0;
        while (poll_sc(cnt) < tgt) {
          __builtin_amdgcn_s_sleep(1);
          if (++guard > (1 << 20)) break;       // watchdog: fail fast, never hang
        }
        if (lane == 0)
          __hip_atomic_store(&step_flag, (u32)t, __ATOMIC_RELAXED,
                             __HIP_MEMORY_SCOPE_WORKGROUP);
      } else {
        int guard = 0;
        while (__hip_atomic_load(&step_flag, __ATOMIC_RELAXED,
                                 __HIP_MEMORY_SCOPE_WORKGROUP) < (u32)t) {
          __builtin_amdgcn_s_sleep(1);
          if (++guard > (1 << 20)) break;
        }
      }
    }

    // ---- issue 16 direct h-fragment loads (L3 RTT hides under x-part) ----
    // at t=0 this reads slot 1 (memset to zero each launch) => h_-1 = 0 exactly
    const char* rds = grpsl + (size_t)((t & 1) ^ 1) * SLOT_BYTES;
    u32x4 av[16];
    aissue(av, rds + afrag);

    AWAIT(16);                                   // x_t complete (A still in flight)
    f32x4 acc[4] = {};
    #pragma unroll
    for (int kc = 0; kc < 8; ++kc) {
      bf16x8 b = __builtin_bit_cast(bf16x8, xreg[kc]);
      #pragma unroll
      for (int nt = 0; nt < 4; ++nt) {
        bf16x8 a = *(const bf16x8*)(smem + ((nt * 24 + kc) * 64 + lane) * 16);
        acc[nt] = __builtin_amdgcn_mfma_f32_16x16x32_bf16(a, b, acc[nt], 0, 0, 0);
      }
    }

    // ---- h-part from pinned weights, counted-vmcnt chunks ----
    AWAIT(12);
    #pragma unroll
    for (int kc = 0; kc < 4; ++kc) {
      bf16x8 b = __builtin_bit_cast(bf16x8, av[kc]);
      #pragma unroll
      for (int nt = 0; nt < 4; ++nt)
        acc[nt] = __builtin_amdgcn_mfma_f32_16x16x32_bf16(bh[kc][nt], b, acc[nt], 0, 0, 0);
    }
    AWAIT(8);
    #pragma unroll
    for (int kc = 4; kc < 8; ++kc) {
      bf16x8 b = __builtin_bit_cast(bf16x8, av[kc]);
      #pragma unroll
      for (int nt = 0; nt < 4; ++nt)
        acc[nt] = __builtin_amdgcn_mfma_f32_16x16x32_bf16(bh[kc][nt], b, acc[nt], 0, 0, 0);
    }
    AWAIT(4);
    #pragma unroll
    for (int kc = 8; kc < 12; ++kc) {
      bf16x8 b = __builtin_bit_cast(bf16x8, av[kc]);
      #pragma unroll
      for (int nt = 0; nt < 4; ++nt)
        acc[nt] = __builtin_amdgcn_mfma_f32_16x16x32_bf16(bh[kc][nt], b, acc[nt], 0, 0, 0);
    }
    AWAIT(0);
    #pragma unroll
    for (int kc = 12; kc < 16; ++kc) {
      bf16x8 b = __builtin_bit_cast(bf16x8, av[kc]);
      #pragma unroll
      for (int nt = 0; nt < 4; ++nt)
        acc[nt] = __builtin_amdgcn_mfma_f32_16x16x32_bf16(bh[kc][nt], b, acc[nt], 0, 0, 0);
    }

    // ---- gates (lane: batch cc, cols hi*4+0..3), pack, ONE dwordx2 store ----
    char* wdst = slices + (size_t)(t & 1) * SLOT_BYTES + grp * GRP_BYTES + wgN * 2048;
    u32 plo = 0, phi2 = 0;
    #pragma unroll
    for (int r = 0; r < 4; ++r) {
      float gi = acc[0][r] + bvn[0][r];
      float gf = acc[1][r] + bvn[1][r];
      float gg = acc[2][r] + bvn[2][r];
      float go = acc[3][r] + bvn[3][r];
      float ii = sigm(gi), ff = sigm(gf), g2 = tanh_(gg), oo = sigm(go);
      float cn = ff * cst[r] + ii * g2;
      cst[r] = cn;
      float hn = oo * tanh_(cn);
      u32 hb = (u32)f2bf(hn);
      if (r < 2) plo |= hb << (16 * r);
      else       phi2 |= hb << (16 * (r - 2));
    }
    u32x2 pk; pk[0] = plo; pk[1] = phi2;
    st8_sc(wdst + (wv * 16 + cc) * 32 + hi * 8, pk);

    AWAIT(0);                                    // own store at coherence point
    __syncthreads();
    if (tid == 0) atomicAdd(cnt, 1u);
    if (t + 1 < NSTEPS)
      xissue(xreg, xrow + (size_t)(t + 1) * 256);   // prefetch next x
  }

  // ---- head: one WG per group computes out = h_T @ W_out^T + b_out ----
  if (wgN == 0) {
    int guard = 0;
    while (poll_sc(cnt) < 32u * NSTEPS) {
      __builtin_amdgcn_s_sleep(1);
      if (++guard > (1 << 20)) break;
    }
    const char* src = grpsl + SLOT_BYTES;        // slot 255&1 = 1
    int b = tid >> 2, q = tid & 3;
    float s = 0.f;
    #pragma unroll
    for (int j16 = 0; j16 < 8; ++j16) {
      int nblk = q * 8 + j16;                    // wgN' block
      const char* p = src + nblk * 2048 + b * 32;
      u32x4 w0 = ld16_sc_wait(p);
      u32x4 w1 = ld16_sc_wait(p + 16);
      #pragma unroll
      for (int d = 0; d < 4; ++d) {
        int jb = q * 128 + j16 * 16 + d * 2;
        s += bf2f((u16)(w0[d] & 0xffff)) * W_out[jb];
        s += bf2f((u16)(w0[d] >> 16))    * W_out[jb + 1];
        s += bf2f((u16)(w1[d] & 0xffff)) * W_out[jb + 8];
        s += bf2f((u16)(w1[d] >> 16))    * W_out[jb + 9];
      }
    }
    s += __shfl_xor(s, 1);
    s += __shfl_xor(s, 2);
    if (q == 0) out[grp * 64 + b] = s + b_out[0];
  }
}

extern "C" void kernel_launch(void* const* d_in, const int* in_sizes, int n_in,
                              void* d_out, int out_size, void* d_ws, size_t ws_size,
                              hipStream_t stream) {
  (void)in_sizes; (void)n_in; (void)out_size; (void)ws_size;
  const float* x     = (const float*)d_in[0];
  const float* W_ih  = (const float*)d_in[1];
  const float* W_hh  = (const float*)d_in[2];
  const float* b_ih  = (const float*)d_in[3];
  const float* b_hh  = (const float*)d_in[4];
  const float* W_out = (const float*)d_in[5];
  const float* b_out = (const float*)d_in[6];
  char* ws = (char*)d_ws;

  // zero h-exchange slots + group counters (re-runs every graph replay)
  hipMemsetAsync(ws + SL_OFF, 0, 2u * SLOT_BYTES + 1024u, stream);
  cvt_x<<<32768, 256, 0, stream>>>(x, (u16*)ws);
  lstm_main<<<256, 256, 0, stream>>>((const u16*)ws, W_ih, W_hh, b_ih, b_hh,
                                     W_out, b_out, (float*)d_out, ws);
}

// Round 14
// 1072.968 us; speedup vs baseline: 1588.9809x; 1.0311x over previous
//
#include <hip/hip_runtime.h>
#include <stdint.h>

typedef unsigned int u32;
typedef unsigned short u16;
typedef __attribute__((ext_vector_type(8))) __bf16 bf16x8;
typedef __attribute__((ext_vector_type(4))) float f32x4;
typedef __attribute__((ext_vector_type(4))) u32 u32x4;
typedef __attribute__((ext_vector_type(2))) u32 u32x2;

#define NSTEPS 256
// ---- workspace layout ----
#define XB_BYTES   67108864u              // x as bf16: 512*256*256*2
#define SL_OFF     XB_BYTES               // h slots: 2 x [group][wgN][row][c16] bf16
#define GRP_BYTES   65536u                // 32 wgN * 2048B
#define SLOT_BYTES  524288u               // 8 groups
#define CNT_OFF    (SL_OFF + 2u * SLOT_BYTES)  // cnt[grp][j]: grp*1024 + j*256 (4 lines/grp)
// ---- LDS: fragment-linear weights ----
#define LDS_TOTAL 98304                   // 4*24*64*16

static __device__ __forceinline__ u16 f2bf(float f) {
  u32 u = __builtin_bit_cast(u32, f);
  return (u16)((u + 0x7fffu + ((u >> 16) & 1u)) >> 16);   // RNE
}
static __device__ __forceinline__ float bf2f(u16 h) {
  u32 u = ((u32)h) << 16;
  return __builtin_bit_cast(float, u);
}
static __device__ __forceinline__ float sigm(float x) {
  return __builtin_amdgcn_rcpf(1.f + __builtin_amdgcn_exp2f(-1.4426950408889634f * x));
}
static __device__ __forceinline__ float tanh_(float x) {
  return 1.f - 2.f * __builtin_amdgcn_rcpf(1.f + __builtin_amdgcn_exp2f(2.8853900817779268f * x));
}

// device-coherent primitives (proven transport: observed-atomic-then-load)
static __device__ __forceinline__ u32 poll_sc(const u32* p) {
  u32 v;
  asm volatile("global_load_dword %0, %1, off sc0 sc1\n\ts_waitcnt vmcnt(0)"
               : "=v"(v) : "v"(p) : "memory");
  return v;
}
static __device__ __forceinline__ void st8_sc(void* p, u32x2 v) {
  asm volatile("global_store_dwordx2 %0, %1, off sc0 sc1" :: "v"(p), "v"(v) : "memory");
}
static __device__ __forceinline__ u32x4 ld16_sc_wait(const void* p) {
  u32x4 v;
  asm volatile("global_load_dwordx4 %0, %1, off sc0 sc1\n\ts_waitcnt vmcnt(0)"
               : "=v"(v) : "v"(p) : "memory");
  return v;
}
// issue 8 cached x loads (no wait)
static __device__ __forceinline__ void xissue(u32x4 x[8], const void* base) {
  asm volatile(
    "global_load_dwordx4 %0, %8, off offset:0\n\t"
    "global_load_dwordx4 %1, %8, off offset:64\n\t"
    "global_load_dwordx4 %2, %8, off offset:128\n\t"
    "global_load_dwordx4 %3, %8, off offset:192\n\t"
    "global_load_dwordx4 %4, %8, off offset:256\n\t"
    "global_load_dwordx4 %5, %8, off offset:320\n\t"
    "global_load_dwordx4 %6, %8, off offset:384\n\t"
    "global_load_dwordx4 %7, %8, off offset:448"
    : "=&v"(x[0]), "=&v"(x[1]), "=&v"(x[2]), "=&v"(x[3]),
      "=&v"(x[4]), "=&v"(x[5]), "=&v"(x[6]), "=&v"(x[7])
    : "v"(base) : "memory");
}
// issue 16 device-coherent h-fragment loads (no wait); stride 4096 B (kc)
static __device__ __forceinline__ void aissue(u32x4 s[16], const char* b) {
  asm volatile(
    "global_load_dwordx4 %0, %16, off sc0 sc1\n\t"
    "global_load_dwordx4 %1, %17, off sc0 sc1\n\t"
    "global_load_dwordx4 %2, %18, off sc0 sc1\n\t"
    "global_load_dwordx4 %3, %19, off sc0 sc1\n\t"
    "global_load_dwordx4 %4, %20, off sc0 sc1\n\t"
    "global_load_dwordx4 %5, %21, off sc0 sc1\n\t"
    "global_load_dwordx4 %6, %22, off sc0 sc1\n\t"
    "global_load_dwordx4 %7, %23, off sc0 sc1\n\t"
    "global_load_dwordx4 %8, %24, off sc0 sc1\n\t"
    "global_load_dwordx4 %9, %25, off sc0 sc1\n\t"
    "global_load_dwordx4 %10, %26, off sc0 sc1\n\t"
    "global_load_dwordx4 %11, %27, off sc0 sc1\n\t"
    "global_load_dwordx4 %12, %28, off sc0 sc1\n\t"
    "global_load_dwordx4 %13, %29, off sc0 sc1\n\t"
    "global_load_dwordx4 %14, %30, off sc0 sc1\n\t"
    "global_load_dwordx4 %15, %31, off sc0 sc1"
    : "=&v"(s[0]), "=&v"(s[1]), "=&v"(s[2]), "=&v"(s[3]),
      "=&v"(s[4]), "=&v"(s[5]), "=&v"(s[6]), "=&v"(s[7]),
      "=&v"(s[8]), "=&v"(s[9]), "=&v"(s[10]), "=&v"(s[11]),
      "=&v"(s[12]), "=&v"(s[13]), "=&v"(s[14]), "=&v"(s[15])
    : "v"(b), "v"(b + 4096), "v"(b + 8192), "v"(b + 12288),
      "v"(b + 16384), "v"(b + 20480), "v"(b + 24576), "v"(b + 28672),
      "v"(b + 32768), "v"(b + 36864), "v"(b + 40960), "v"(b + 45056),
      "v"(b + 49152), "v"(b + 53248), "v"(b + 57344), "v"(b + 61440)
    : "memory");
}
#define AWAIT(N) do { asm volatile("s_waitcnt vmcnt(" #N ")" ::: "memory"); \
                      __builtin_amdgcn_sched_barrier(0); } while (0)

__global__ void cvt_x(const float* __restrict__ x, u16* __restrict__ xb) {
  int i = blockIdx.x * 256 + threadIdx.x;          // one float4 per thread
  float4 v = ((const float4*)x)[i];
  ushort4 o;
  o.x = f2bf(v.x); o.y = f2bf(v.y); o.z = f2bf(v.z); o.w = f2bf(v.w);
  ((ushort4*)xb)[i] = o;
}

// 256 WGs: group = wg&7 (batch rows [grp*64,+64)), wgN = wg>>3 (hidden cols
// [wgN*16,+16) of all 4 gates). Swapped MFMA (D = W·X^T). R14 delta vs R13:
// the group step-counter is SPLIT ACROSS 4 SEPARATE CACHE LINES (256B apart);
// producer wgN signals line wgN&3 (8 RMWs/line/step instead of 32 on one) and
// wave 0 polls all 4 lines in one per-lane load. Signal kind unchanged
// (store -> vmcnt(0) -> atomicAdd; consumers load only after observing).
__global__ void __launch_bounds__(256, 1) lstm_main(
    const u16* __restrict__ xb,
    const float* __restrict__ W_ih, const float* __restrict__ W_hh,
    const float* __restrict__ b_ih, const float* __restrict__ b_hh,
    const float* __restrict__ W_out, const float* __restrict__ b_out,
    float* __restrict__ out, char* __restrict__ ws)
{
  __shared__ char smem[LDS_TOTAL];
  __shared__ u32 step_flag;
  const int tid = threadIdx.x;
  const int wg  = blockIdx.x;
  const int grp = wg & 7;
  const int wgN = wg >> 3;
  const int lane = tid & 63;
  const int wv   = tid >> 6;
  const int cc = lane & 15;
  const int hi = lane >> 4;

  if (tid == 0) step_flag = 0;

  // ---- one-time: weight slice -> LDS, fragment-linear (conflict-free) ----
  {
    const int lc = lane & 15, hh = lane >> 4;
    #pragma unroll
    for (int nt = 0; nt < 4; ++nt)
      #pragma unroll
      for (int it = 0; it < 6; ++it) {
        int kcc = wv + it * 4;                  // 0..23
        int n = nt * 512 + wgN * 16 + lc;
        int k = kcc * 32 + hh * 8;
        float4 v0, v1;
        if (kcc < 8) {
          v0 = *(const float4*)(W_ih + n * 256 + k);
          v1 = *(const float4*)(W_ih + n * 256 + k + 4);
        } else {
          int k2 = k - 256;
          v0 = *(const float4*)(W_hh + n * 512 + k2);
          v1 = *(const float4*)(W_hh + n * 512 + k2 + 4);
        }
        u32x4 g;
        g[0] = (u32)f2bf(v0.x) | ((u32)f2bf(v0.y) << 16);
        g[1] = (u32)f2bf(v0.z) | ((u32)f2bf(v0.w) << 16);
        g[2] = (u32)f2bf(v1.x) | ((u32)f2bf(v1.y) << 16);
        g[3] = (u32)f2bf(v1.z) | ((u32)f2bf(v1.w) << 16);
        *(u32x4*)(smem + ((nt * 24 + kcc) * 64 + lane) * 16) = g;
      }
  }

  float bvn[4][4];
  #pragma unroll
  for (int nt = 0; nt < 4; ++nt)
    #pragma unroll
    for (int r = 0; r < 4; ++r) {
      int n = nt * 512 + wgN * 16 + hi * 4 + r;
      bvn[nt][r] = b_ih[n] + b_hh[n];
    }

  u32* cnt = (u32*)(ws + CNT_OFF + grp * 1024);  // 4 lines, 256B apart
  const u32* mypoll = cnt + (lane & 3) * 64;     // lane j polls line j&3
  u32* mysig = cnt + (wgN & 3) * 64;             // producer's signal line
  char* slices = ws + SL_OFF;
  const char* grpsl = slices + (size_t)grp * GRP_BYTES;

  const u16* xrow = xb + (size_t)(grp * 64 + wv * 16 + cc) * 65536 + hi * 8;
  // A-fragment per-lane base inside slot (stride 4096 per kc)
  const int afrag = (hi >> 1) * 2048 + (wv * 16 + cc) * 32 + (hi & 1) * 16;

  __syncthreads();

  // ---- pin h-part weight fragments in 256 regs (kc 8..23 of full row) ----
  bf16x8 bh[16][4];
  #pragma unroll
  for (int kc = 0; kc < 16; ++kc)
    #pragma unroll
    for (int nt = 0; nt < 4; ++nt)
      bh[kc][nt] = *(const bf16x8*)(smem + ((nt * 24 + kc + 8) * 64 + lane) * 16);
  #pragma unroll
  for (int kc = 0; kc < 16; ++kc)
    #pragma unroll
    for (int nt = 0; nt < 4; ++nt)
      asm volatile("" : "+v"(bh[kc][nt]));      // opaque: forbid remat, force regs

  float cst[4] = {0.f, 0.f, 0.f, 0.f};          // fp32 cell state

  u32x4 xreg[8];
  xissue(xreg, xrow);                            // prefetch x_0

  #pragma unroll 1
  for (int t = 0; t < NSTEPS; ++t) {
    if (t > 0) {
      u32 tgt = 8u * (u32)t;                     // per-line target (8 producers)
      if (wv == 0) {
        int guard = 0;
        for (;;) {
          u32 v = poll_sc(mypoll);               // 4 lines, one per lane&3
          if (__all((int)(v >= tgt))) break;
          if (++guard > (1 << 20)) break;        // watchdog: fail fast, never hang
        }
        if (lane == 0)
          __hip_atomic_store(&step_flag, (u32)t, __ATOMIC_RELAXED,
                             __HIP_MEMORY_SCOPE_WORKGROUP);
      } else {
        int guard = 0;
        while (__hip_atomic_load(&step_flag, __ATOMIC_RELAXED,
                                 __HIP_MEMORY_SCOPE_WORKGROUP) < (u32)t) {
          __builtin_amdgcn_s_sleep(1);
          if (++guard > (1 << 20)) break;
        }
      }
    }

    // ---- issue 16 direct h-fragment loads (L3 RTT hides under x-part) ----
    // at t=0 this reads slot 1 (memset to zero each launch) => h_-1 = 0 exactly
    const char* rds = grpsl + (size_t)((t & 1) ^ 1) * SLOT_BYTES;
    u32x4 av[16];
    aissue(av, rds + afrag);

    AWAIT(16);                                   // x_t complete (A still in flight)
    f32x4 acc[4] = {};
    #pragma unroll
    for (int kc = 0; kc < 8; ++kc) {
      bf16x8 b = __builtin_bit_cast(bf16x8, xreg[kc]);
      #pragma unroll
      for (int nt = 0; nt < 4; ++nt) {
        bf16x8 a = *(const bf16x8*)(smem + ((nt * 24 + kc) * 64 + lane) * 16);
        acc[nt] = __builtin_amdgcn_mfma_f32_16x16x32_bf16(a, b, acc[nt], 0, 0, 0);
      }
    }

    // ---- h-part from pinned weights, counted-vmcnt chunks ----
    AWAIT(12);
    #pragma unroll
    for (int kc = 0; kc < 4; ++kc) {
      bf16x8 b = __builtin_bit_cast(bf16x8, av[kc]);
      #pragma unroll
      for (int nt = 0; nt < 4; ++nt)
        acc[nt] = __builtin_amdgcn_mfma_f32_16x16x32_bf16(bh[kc][nt], b, acc[nt], 0, 0, 0);
    }
    AWAIT(8);
    #pragma unroll
    for (int kc = 4; kc < 8; ++kc) {
      bf16x8 b = __builtin_bit_cast(bf16x8, av[kc]);
      #pragma unroll
      for (int nt = 0; nt < 4; ++nt)
        acc[nt] = __builtin_amdgcn_mfma_f32_16x16x32_bf16(bh[kc][nt], b, acc[nt], 0, 0, 0);
    }
    AWAIT(4);
    #pragma unroll
    for (int kc = 8; kc < 12; ++kc) {
      bf16x8 b = __builtin_bit_cast(bf16x8, av[kc]);
      #pragma unroll
      for (int nt = 0; nt < 4; ++nt)
        acc[nt] = __builtin_amdgcn_mfma_f32_16x16x32_bf16(bh[kc][nt], b, acc[nt], 0, 0, 0);
    }
    AWAIT(0);
    #pragma unroll
    for (int kc = 12; kc < 16; ++kc) {
      bf16x8 b = __builtin_bit_cast(bf16x8, av[kc]);
      #pragma unroll
      for (int nt = 0; nt < 4; ++nt)
        acc[nt] = __builtin_amdgcn_mfma_f32_16x16x32_bf16(bh[kc][nt], b, acc[nt], 0, 0, 0);
    }

    // ---- gates (lane: batch cc, cols hi*4+0..3), pack, ONE dwordx2 store ----
    char* wdst = slices + (size_t)(t & 1) * SLOT_BYTES + grp * GRP_BYTES + wgN * 2048;
    u32 plo = 0, phi2 = 0;
    #pragma unroll
    for (int r = 0; r < 4; ++r) {
      float gi = acc[0][r] + bvn[0][r];
      float gf = acc[1][r] + bvn[1][r];
      float gg = acc[2][r] + bvn[2][r];
      float go = acc[3][r] + bvn[3][r];
      float ii = sigm(gi), ff = sigm(gf), g2 = tanh_(gg), oo = sigm(go);
      float cn = ff * cst[r] + ii * g2;
      cst[r] = cn;
      float hn = oo * tanh_(cn);
      u32 hb = (u32)f2bf(hn);
      if (r < 2) plo |= hb << (16 * r);
      else       phi2 |= hb << (16 * (r - 2));
    }
    u32x2 pk; pk[0] = plo; pk[1] = phi2;
    st8_sc(wdst + (wv * 16 + cc) * 32 + hi * 8, pk);

    AWAIT(0);                                    // own store at coherence point
    __syncthreads();
    if (tid == 0) atomicAdd(mysig, 1u);          // signal on spread line
    if (t + 1 < NSTEPS)
      xissue(xreg, xrow + (size_t)(t + 1) * 256);   // prefetch next x
  }

  // ---- head: one WG per group computes out = h_T @ W_out^T + b_out ----
  if (wgN == 0) {
    {
      const u32* hp = cnt + (lane & 3) * 64;
      int guard = 0;
      for (;;) {
        u32 v = poll_sc(hp);
        if (__all((int)(v >= 8u * NSTEPS))) break;
        if (++guard > (1 << 20)) break;
      }
    }
    const char* src = grpsl + SLOT_BYTES;        // slot 255&1 = 1
    int b = tid >> 2, q = tid & 3;
    float s = 0.f;
    #pragma unroll
    for (int j16 = 0; j16 < 8; ++j16) {
      int nblk = q * 8 + j16;                    // wgN' block
      const char* p = src + nblk * 2048 + b * 32;
      u32x4 w0 = ld16_sc_wait(p);
      u32x4 w1 = ld16_sc_wait(p + 16);
      #pragma unroll
      for (int d = 0; d < 4; ++d) {
        int jb = q * 128 + j16 * 16 + d * 2;
        s += bf2f((u16)(w0[d] & 0xffff)) * W_out[jb];
        s += bf2f((u16)(w0[d] >> 16))    * W_out[jb + 1];
        s += bf2f((u16)(w1[d] & 0xffff)) * W_out[jb + 8];
        s += bf2f((u16)(w1[d] >> 16))    * W_out[jb + 9];
      }
    }
    s += __shfl_xor(s, 1);
    s += __shfl_xor(s, 2);
    if (q == 0) out[grp * 64 + b] = s + b_out[0];
  }
}

extern "C" void kernel_launch(void* const* d_in, const int* in_sizes, int n_in,
                              void* d_out, int out_size, void* d_ws, size_t ws_size,
                              hipStream_t stream) {
  (void)in_sizes; (void)n_in; (void)out_size; (void)ws_size;
  const float* x     = (const float*)d_in[0];
  const float* W_ih  = (const float*)d_in[1];
  const float* W_hh  = (const float*)d_in[2];
  const float* b_ih  = (const float*)d_in[3];
  const float* b_hh  = (const float*)d_in[4];
  const float* W_out = (const float*)d_in[5];
  const float* b_out = (const float*)d_in[6];
  char* ws = (char*)d_ws;

  // zero h-exchange slots + spread counters (re-runs every graph replay)
  hipMemsetAsync(ws + SL_OFF, 0, 2u * SLOT_BYTES + 8192u, stream);
  cvt_x<<<32768, 256, 0, stream>>>(x, (u16*)ws);
  lstm_main<<<256, 256, 0, stream>>>((const u16*)ws, W_ih, W_hh, b_ih, b_hh,
                                     W_out, b_out, (float*)d_out, ws);
}